// Round 4
// baseline (658.381 us; speedup 1.0000x reference)
//
#include <hip/hip_runtime.h>
#include <hip/hip_bf16.h>

#define NN 50000
#define HH 4
#define RR 3
#define EE 524288      // 2^19
#define ESHIFT 19
#define TN (RR*NN)     // 150000
#define NCHUNK ((TN + 1023)/1024)  // 147

typedef __attribute__((ext_vector_type(8))) short short8;
typedef __attribute__((ext_vector_type(4))) float float4v;

// ---------------- conversion kernels ----------------

__global__ void conv_bf16_kernel(const float* __restrict__ in, __hip_bfloat16* __restrict__ out, int n) {
    int i = blockIdx.x * 256 + threadIdx.x;
    if (i < n) out[i] = __float2bfloat16(in[i]);
}

// W: [3][128][NC] f32 -> T: [3*2*NC rows][128] bf16; row (r*2*NC + colOff + n), col k.
__global__ void transpose_w_kernel(const float* __restrict__ W, __hip_bfloat16* __restrict__ T,
                                   int NC, int colOff) {
    int i = blockIdx.x * 256 + threadIdx.x;   // exact: 3*128*NC
    int per = 128 * NC;
    int r = i / per;
    int rem = i - r * per;
    int k = rem / NC;
    int n = rem - k * NC;
    T[(size_t)(r * 2 * NC + colOff + n) * 128 + k] = __float2bfloat16(W[i]);
}

// ---------------- CSR build ----------------

__global__ void hist_kernel(const int* __restrict__ dst, int* __restrict__ deg) {
    int i = blockIdx.x * 256 + threadIdx.x;   // < 3E exact
    int r = i >> ESHIFT;
    atomicAdd(&deg[r * NN + dst[i]], 1);
}

__global__ void scan1_kernel(const int* __restrict__ deg, int* __restrict__ part) {
    __shared__ int s[256];
    int t = threadIdx.x;
    int base = blockIdx.x * 1024 + t * 4;
    int sum = 0;
#pragma unroll
    for (int j = 0; j < 4; j++) {
        int idx = base + j;
        sum += (idx < TN) ? deg[idx] : 0;
    }
    s[t] = sum;
    __syncthreads();
    for (int off = 128; off > 0; off >>= 1) {
        if (t < off) s[t] += s[t + off];
        __syncthreads();
    }
    if (t == 0) part[blockIdx.x] = s[0];
}

__global__ void scan2_kernel(int* part) {
    int run = 0;
    for (int i = 0; i < NCHUNK; i++) {
        int v = part[i];
        part[i] = run;
        run += v;
    }
}

__global__ void scan3_kernel(const int* __restrict__ deg, const int* __restrict__ part,
                             int* __restrict__ offs, int* __restrict__ curs) {
    __shared__ int s[256];
    int t = threadIdx.x;
    int base = blockIdx.x * 1024 + t * 4;
    int v[4];
    int tsum = 0;
#pragma unroll
    for (int j = 0; j < 4; j++) {
        int idx = base + j;
        v[j] = (idx < TN) ? deg[idx] : 0;
        tsum += v[j];
    }
    s[t] = tsum;
    __syncthreads();
    for (int off = 1; off < 256; off <<= 1) {
        int x = (t >= off) ? s[t - off] : 0;
        __syncthreads();
        s[t] += x;
        __syncthreads();
    }
    int excl = s[t] - tsum + part[blockIdx.x];
    int run = excl;
#pragma unroll
    for (int j = 0; j < 4; j++) {
        int idx = base + j;
        if (idx < TN) {
            offs[idx] = run;
            curs[idx] = run;
            run += v[j];
        }
    }
}

// Pass-split scatter: blockIdx.y = dst-range pass (4 x 12500 nodes).
// Only matching edges write -> random stores land in a ~1.6MB L2-resident esrc window.
__global__ void scatter_kernel(const int* __restrict__ src, const int* __restrict__ dst,
                               int* __restrict__ curs, int* __restrict__ esrc) {
    int i = blockIdx.x * 256 + threadIdx.x;   // < 3E exact
    int p = blockIdx.y;
    int d = dst[i];
    if ((unsigned)(d - p * 12500) < 12500u) {
        int r = i >> ESHIFT;
        int pos = atomicAdd(&curs[r * NN + d], 1);
        esrc[pos] = src[i];
    }
}

// ---------------- GEMM ----------------
// C tables layout: 6 tables [M, NCsub] bf16, table id = global_col >> nshift
// (order: r0_src, r0_dst, r1_src, r1_dst, r2_src, r2_dst).

__launch_bounds__(256)
__global__ void gemm_kernel(const __hip_bfloat16* __restrict__ A,
                            const __hip_bfloat16* __restrict__ Bt,   // [NCtot,128]
                            __hip_bfloat16* __restrict__ C,
                            int M, int nshift) {
    __shared__ __hip_bfloat16 Bs[64 * 136];
    int tile_m = blockIdx.x * 64;
    int tile_n = blockIdx.y * 64;
    int t = threadIdx.x;

    {
        const uint4* gsrc = (const uint4*)(Bt + (size_t)tile_n * 128);
        for (int e = t; e < 64 * 16; e += 256) {
            int n = e >> 4, c = e & 15;
            uint4 val = gsrc[n * 16 + c];
            *(uint4*)(&Bs[n * 136 + c * 8]) = val;
        }
    }
    __syncthreads();

    int w = t >> 6, lane = t & 63;
    int m16 = lane & 15, quad = lane >> 4;
    int row = tile_m + w * 16 + m16;
    int rowc = row < M ? row : M - 1;

    short8 a[4];
    const short8* ap = (const short8*)(A + (size_t)rowc * 128);
#pragma unroll
    for (int kf = 0; kf < 4; kf++) a[kf] = ap[quad + kf * 4];

    float4v acc[4];
#pragma unroll
    for (int ct = 0; ct < 4; ct++) {
        acc[ct] = (float4v){0.f, 0.f, 0.f, 0.f};
        const short8* bp = (const short8*)(Bs + (ct * 16 + m16) * 136);
#pragma unroll
        for (int kf = 0; kf < 4; kf++) {
            short8 b = bp[quad + kf * 4];
            acc[ct] = __builtin_amdgcn_mfma_f32_16x16x32_bf16(a[kf], b, acc[ct], 0, 0, 0);
        }
    }

    int cmask = (1 << nshift) - 1;
#pragma unroll
    for (int ct = 0; ct < 4; ct++) {
        int col = tile_n + ct * 16 + m16;
        int tbl = col >> nshift;
        int cc = col & cmask;
        size_t base = ((size_t)tbl * M) << nshift;
#pragma unroll
        for (int rg = 0; rg < 4; rg++) {
            int rr = tile_m + w * 16 + quad * 4 + rg;
            if (rr < M) C[base + (((size_t)rr) << nshift) + cc] = __float2bfloat16(acc[ct][rg]);
        }
    }
}

// ---------------- fused per-node softmax + aggregation ----------------
// One wave per node; wave = 4 edge-groups (g = lane>>4) x 16 channel-slices (c = lane&15).
// V = channels/lane = NC/16 (L1: 8, L2: 16). Head = c>>2 (4 c-lanes per head).
// 4 edges processed per loop iteration; score reduce = 2 shuffles per 4 edges;
// invalid edge slots predicated (p=0) -> no tail loop. Cross-group combine in epilogue.

template <int V>
__device__ inline void ldrow(const ushort* __restrict__ p, float* hv) {
#pragma unroll
    for (int w = 0; w < V / 8; w++) {
        uint4 pk = ((const uint4*)p)[w];
        hv[w * 8 + 0] = __uint_as_float(pk.x << 16);
        hv[w * 8 + 1] = __uint_as_float(pk.x & 0xffff0000u);
        hv[w * 8 + 2] = __uint_as_float(pk.y << 16);
        hv[w * 8 + 3] = __uint_as_float(pk.y & 0xffff0000u);
        hv[w * 8 + 4] = __uint_as_float(pk.z << 16);
        hv[w * 8 + 5] = __uint_as_float(pk.z & 0xffff0000u);
        hv[w * 8 + 6] = __uint_as_float(pk.w << 16);
        hv[w * 8 + 7] = __uint_as_float(pk.w & 0xffff0000u);
    }
}

template <int V, bool L1>
__launch_bounds__(256)
__global__ void agg_kernel(const ushort* __restrict__ C,
                           const float* __restrict__ a,            // [R][NC]
                           const int* __restrict__ offs, const int* __restrict__ deg,
                           const int* __restrict__ esrc,
                           float* __restrict__ outf, __hip_bfloat16* __restrict__ outb) {
    const int NC = 16 * V;
    int wid = (blockIdx.x * 256 + threadIdx.x) >> 6;  // node id, < 50000 exact
    int lane = threadIdx.x & 63;
    int g = lane >> 4;
    int c = lane & 15;
    int eb = c * V;

    float total[V];
#pragma unroll
    for (int j = 0; j < V; j++) total[j] = 0.f;

#pragma unroll 1
    for (int r = 0; r < RR; r++) {
        const ushort* hsb = C + ((size_t)(2 * r) * NN) * NC;
        const ushort* hdb = C + ((size_t)(2 * r + 1) * NN) * NC;
        float hdv[V], al[V], acc[V];
        ldrow<V>(hdb + (size_t)wid * NC + eb, hdv);
#pragma unroll
        for (int j = 0; j < V; j++) {
            al[j] = a[r * NC + eb + j];
            acc[j] = 0.f;
        }
        float den = 0.f;
        int e0 = offs[r * NN + wid];
        int dg = deg[r * NN + wid];
        int elast = e0 + dg - 1;
        int nit = (dg + 3) >> 2;
        for (int it = 0; it < nit; ++it) {
            int k = (it << 2) + g;
            int idx = e0 + k;
            int u = esrc[min(idx, elast)];
            bool valid = k < dg;
            float hv[V];
            ldrow<V>(hsb + (size_t)u * NC + eb, hv);
            float s0 = 0.f, s1 = 0.f;
#pragma unroll
            for (int j = 0; j < V; j += 2) {
                float m0 = hv[j] + hdv[j];
                float m1 = hv[j + 1] + hdv[j + 1];
                s0 = fmaf(fmaxf(m0, 0.2f * m0), al[j], s0);
                s1 = fmaf(fmaxf(m1, 0.2f * m1), al[j + 1], s1);
            }
            float s = s0 + s1;
            s += __shfl_xor(s, 1);
            s += __shfl_xor(s, 2);
            float p = valid ? __expf(s) : 0.f;
            den += p;
#pragma unroll
            for (int j = 0; j < V; j++) acc[j] += p * hv[j];
        }
        // combine the 4 edge-groups
        den += __shfl_xor(den, 16);
        den += __shfl_xor(den, 32);
        float inv = 1.f / (den + 1e-9f);
#pragma unroll
        for (int j = 0; j < V; j++) {
            float tt = acc[j] + __shfl_xor(acc[j], 16);
            tt += __shfl_xor(tt, 32);
            total[j] += tt * inv;
        }
    }

    if (g == 0) {
        if constexpr (L1) {
#pragma unroll
            for (int j = 0; j < V; j++) {
                float v = total[j];
                outb[(size_t)wid * NC + eb + j] = __float2bfloat16(v > 0.f ? v : 0.f);
            }
        } else {
#pragma unroll
            for (int j = 0; j < V; j++) outf[(size_t)wid * NC + eb + j] = total[j];
        }
    }
}

// ---------------- launch ----------------

extern "C" void kernel_launch(void* const* d_in, const int* in_sizes, int n_in,
                              void* d_out, int out_size, void* d_ws, size_t ws_size,
                              hipStream_t stream) {
    const float* x   = (const float*)d_in[0];
    const int*   src = (const int*)d_in[1];
    const int*   dst = (const int*)d_in[2];
    const float* W1s = (const float*)d_in[3];
    const float* W1d = (const float*)d_in[4];
    const float* a1  = (const float*)d_in[5];
    const float* W2s = (const float*)d_in[6];
    const float* W2d = (const float*)d_in[7];
    const float* a2  = (const float*)d_in[8];

    char* ws = (char*)d_ws;
    size_t off = 0;
    auto alloc = [&](size_t bytes) -> void* {
        void* p = ws + off;
        off += (bytes + 255) & ~(size_t)255;
        return p;
    };
    __hip_bfloat16* xb = (__hip_bfloat16*)alloc((size_t)NN * 128 * 2);
    __hip_bfloat16* hb = (__hip_bfloat16*)alloc((size_t)NN * 128 * 2);
    __hip_bfloat16* Cb = (__hip_bfloat16*)alloc((size_t)NN * 1536 * 2);  // 6 tables; L1 [N,128]x6, L2 [N,256]x6
    __hip_bfloat16* T1 = (__hip_bfloat16*)alloc((size_t)768 * 128 * 2);
    __hip_bfloat16* T2 = (__hip_bfloat16*)alloc((size_t)1536 * 128 * 2);
    int* deg  = (int*)alloc((size_t)TN * 4);
    int* offs = (int*)alloc((size_t)TN * 4);
    int* curs = (int*)alloc((size_t)TN * 4);
    int* esrc = (int*)alloc((size_t)RR * EE * 4);
    int* part = (int*)alloc(4096);

    float* outp = (float*)d_out;

    // conversions / weight packing
    conv_bf16_kernel<<<25000, 256, 0, stream>>>(x, xb, NN * 128);
    transpose_w_kernel<<<192, 256, 0, stream>>>(W1s, T1, 128, 0);
    transpose_w_kernel<<<192, 256, 0, stream>>>(W1d, T1, 128, 128);
    transpose_w_kernel<<<384, 256, 0, stream>>>(W2s, T2, 256, 0);
    transpose_w_kernel<<<384, 256, 0, stream>>>(W2d, T2, 256, 256);

    // CSR build (shared by both layers)
    hipMemsetAsync(deg, 0, (size_t)TN * 4, stream);
    hist_kernel<<<(RR * EE) / 256, 256, 0, stream>>>(dst, deg);
    scan1_kernel<<<NCHUNK, 256, 0, stream>>>(deg, part);
    scan2_kernel<<<1, 1, 0, stream>>>(part);
    scan3_kernel<<<NCHUNK, 256, 0, stream>>>(deg, part, offs, curs);
    scatter_kernel<<<dim3((RR * EE) / 256, 4), 256, 0, stream>>>(src, dst, curs, esrc);

    // Layer 1: GEMM [N,128]x[128,768] -> 6 compact [N,128] tables; agg fuses relu+bf16 -> hb
    gemm_kernel<<<dim3(782, 12), 256, 0, stream>>>(xb, T1, Cb, NN, 7);
    agg_kernel<8, true><<<12500, 256, 0, stream>>>((const ushort*)Cb, a1, offs, deg, esrc,
                                                   nullptr, hb);

    // Layer 2: GEMM [N,128]x[128,1536] -> 6 compact [N,256] tables; agg -> f32 d_out
    gemm_kernel<<<dim3(782, 24), 256, 0, stream>>>(hb, T2, Cb, NN, 8);
    agg_kernel<16, false><<<12500, 256, 0, stream>>>((const ushort*)Cb, a2, offs, deg, esrc,
                                                     outp, nullptr);
}

// Round 5
// 639.046 us; speedup vs baseline: 1.0303x; 1.0303x over previous
//
#include <hip/hip_runtime.h>
#include <hip/hip_bf16.h>

#define NN 50000
#define HH 4
#define RR 3
#define EE 524288      // 2^19
#define ESHIFT 19
#define TN (RR*NN)     // 150000
#define NCHUNK ((TN + 1023)/1024)  // 147

typedef __attribute__((ext_vector_type(8))) short short8;
typedef __attribute__((ext_vector_type(4))) float float4v;
typedef __attribute__((ext_vector_type(2))) float float2v;

// ---------------- conversion kernels ----------------

__global__ void conv_bf16_kernel(const float* __restrict__ in, __hip_bfloat16* __restrict__ out, int n) {
    int i = blockIdx.x * 256 + threadIdx.x;
    if (i < n) out[i] = __float2bfloat16(in[i]);
}

// W: [3][128][NC] f32 -> T: [3*2*NC rows][128] bf16; row (r*2*NC + colOff + n), col k.
__global__ void transpose_w_kernel(const float* __restrict__ W, __hip_bfloat16* __restrict__ T,
                                   int NC, int colOff) {
    int i = blockIdx.x * 256 + threadIdx.x;   // exact: 3*128*NC
    int per = 128 * NC;
    int r = i / per;
    int rem = i - r * per;
    int k = rem / NC;
    int n = rem - k * NC;
    T[(size_t)(r * 2 * NC + colOff + n) * 128 + k] = __float2bfloat16(W[i]);
}

// ---------------- CSR build ----------------

__global__ void hist_kernel(const int* __restrict__ dst, int* __restrict__ deg) {
    int i = blockIdx.x * 256 + threadIdx.x;   // < 3E exact
    int r = i >> ESHIFT;
    atomicAdd(&deg[r * NN + dst[i]], 1);
}

__global__ void scan1_kernel(const int* __restrict__ deg, int* __restrict__ part) {
    __shared__ int s[256];
    int t = threadIdx.x;
    int base = blockIdx.x * 1024 + t * 4;
    int sum = 0;
#pragma unroll
    for (int j = 0; j < 4; j++) {
        int idx = base + j;
        sum += (idx < TN) ? deg[idx] : 0;
    }
    s[t] = sum;
    __syncthreads();
    for (int off = 128; off > 0; off >>= 1) {
        if (t < off) s[t] += s[t + off];
        __syncthreads();
    }
    if (t == 0) part[blockIdx.x] = s[0];
}

__global__ void scan2_kernel(int* part) {
    int run = 0;
    for (int i = 0; i < NCHUNK; i++) {
        int v = part[i];
        part[i] = run;
        run += v;
    }
}

__global__ void scan3_kernel(const int* __restrict__ deg, const int* __restrict__ part,
                             int* __restrict__ offs, int* __restrict__ curs) {
    __shared__ int s[256];
    int t = threadIdx.x;
    int base = blockIdx.x * 1024 + t * 4;
    int v[4];
    int tsum = 0;
#pragma unroll
    for (int j = 0; j < 4; j++) {
        int idx = base + j;
        v[j] = (idx < TN) ? deg[idx] : 0;
        tsum += v[j];
    }
    s[t] = tsum;
    __syncthreads();
    for (int off = 1; off < 256; off <<= 1) {
        int x = (t >= off) ? s[t - off] : 0;
        __syncthreads();
        s[t] += x;
        __syncthreads();
    }
    int excl = s[t] - tsum + part[blockIdx.x];
    int run = excl;
#pragma unroll
    for (int j = 0; j < 4; j++) {
        int idx = base + j;
        if (idx < TN) {
            offs[idx] = run;
            curs[idx] = run;
            run += v[j];
        }
    }
}

// Pass-split scatter: blockIdx.y = dst-range pass (4 x 12500 nodes) -> L2-resident write window.
__global__ void scatter_kernel(const int* __restrict__ src, const int* __restrict__ dst,
                               int* __restrict__ curs, int* __restrict__ esrc) {
    int i = blockIdx.x * 256 + threadIdx.x;   // < 3E exact
    int p = blockIdx.y;
    int d = dst[i];
    if ((unsigned)(d - p * 12500) < 12500u) {
        int r = i >> ESHIFT;
        int pos = atomicAdd(&curs[r * NN + d], 1);
        esrc[pos] = src[i];
    }
}

// ---------------- GEMM ----------------
// C tables layout: 6 tables [M, NCsub] bf16, table id = global_col >> nshift
// (order: r0_src, r0_dst, r1_src, r1_dst, r2_src, r2_dst).

__launch_bounds__(256)
__global__ void gemm_kernel(const __hip_bfloat16* __restrict__ A,
                            const __hip_bfloat16* __restrict__ Bt,   // [NCtot,128]
                            __hip_bfloat16* __restrict__ C,
                            int M, int nshift) {
    __shared__ __hip_bfloat16 Bs[64 * 136];
    int tile_m = blockIdx.x * 64;
    int tile_n = blockIdx.y * 64;
    int t = threadIdx.x;

    {
        const uint4* gsrc = (const uint4*)(Bt + (size_t)tile_n * 128);
        for (int e = t; e < 64 * 16; e += 256) {
            int n = e >> 4, c = e & 15;
            uint4 val = gsrc[n * 16 + c];
            *(uint4*)(&Bs[n * 136 + c * 8]) = val;
        }
    }
    __syncthreads();

    int w = t >> 6, lane = t & 63;
    int m16 = lane & 15, quad = lane >> 4;
    int row = tile_m + w * 16 + m16;
    int rowc = row < M ? row : M - 1;

    short8 a[4];
    const short8* ap = (const short8*)(A + (size_t)rowc * 128);
#pragma unroll
    for (int kf = 0; kf < 4; kf++) a[kf] = ap[quad + kf * 4];

    float4v acc[4];
#pragma unroll
    for (int ct = 0; ct < 4; ct++) {
        acc[ct] = (float4v){0.f, 0.f, 0.f, 0.f};
        const short8* bp = (const short8*)(Bs + (ct * 16 + m16) * 136);
#pragma unroll
        for (int kf = 0; kf < 4; kf++) {
            short8 b = bp[quad + kf * 4];
            acc[ct] = __builtin_amdgcn_mfma_f32_16x16x32_bf16(a[kf], b, acc[ct], 0, 0, 0);
        }
    }

    int cmask = (1 << nshift) - 1;
#pragma unroll
    for (int ct = 0; ct < 4; ct++) {
        int col = tile_n + ct * 16 + m16;
        int tbl = col >> nshift;
        int cc = col & cmask;
        size_t base = ((size_t)tbl * M) << nshift;
#pragma unroll
        for (int rg = 0; rg < 4; rg++) {
            int rr = tile_m + w * 16 + quad * 4 + rg;
            if (rr < M) C[base + (((size_t)rr) << nshift) + cc] = __float2bfloat16(acc[ct][rg]);
        }
    }
}

// ---------------- fused per-node softmax + aggregation ----------------
// One wave per node; wave = 2 edge-groups (g = lane>>5) x 32 channel-slices (c = lane&31).
// V = channels/lane = NC/32 (L1: 4, L2: 8); W2 = V/2 float2 regs.
// head = c>>3 (8 lanes per head) -> score reduce = shfl_xor 1,2,4 (both layers).
// Edge loop: 4 edges per iteration (2 groups x unroll 2) = 2 independent chains/lane.
// Packed float2 arithmetic -> v_pk_add/mul/fma_f32.

template <int W2>
__device__ inline void ldrow(const ushort* __restrict__ p, float2v* hv) {
    if constexpr (W2 == 2) {   // V=4: 8 bytes
        uint2 pk = *(const uint2*)p;
        hv[0] = (float2v){__uint_as_float(pk.x << 16), __uint_as_float(pk.x & 0xffff0000u)};
        hv[1] = (float2v){__uint_as_float(pk.y << 16), __uint_as_float(pk.y & 0xffff0000u)};
    } else {                   // V=8: 16 bytes
        uint4 pk = *(const uint4*)p;
        hv[0] = (float2v){__uint_as_float(pk.x << 16), __uint_as_float(pk.x & 0xffff0000u)};
        hv[1] = (float2v){__uint_as_float(pk.y << 16), __uint_as_float(pk.y & 0xffff0000u)};
        hv[2] = (float2v){__uint_as_float(pk.z << 16), __uint_as_float(pk.z & 0xffff0000u)};
        hv[3] = (float2v){__uint_as_float(pk.w << 16), __uint_as_float(pk.w & 0xffff0000u)};
    }
}

template <int W2>
__device__ inline float edot(const float2v* hv, const float2v* hdv, const float2v* al) {
    float2v s = (float2v){0.f, 0.f};
#pragma unroll
    for (int j = 0; j < W2; j++) {
        float2v m = hv[j] + hdv[j];
        float2v lr = __builtin_elementwise_max(m, 0.2f * m);
        s += lr * al[j];
    }
    return s.x + s.y;
}

__device__ inline float hred8(float s) {
    s += __shfl_xor(s, 1);
    s += __shfl_xor(s, 2);
    s += __shfl_xor(s, 4);
    return s;
}

template <int W2, bool L1>
__launch_bounds__(256)
__global__ void agg_kernel(const ushort* __restrict__ C,
                           const float* __restrict__ a,            // [R][NC]
                           const int* __restrict__ offs, const int* __restrict__ deg,
                           const int* __restrict__ esrc,
                           float* __restrict__ outf, __hip_bfloat16* __restrict__ outb) {
    const int V = 2 * W2;
    const int NC = 32 * V;
    int wid = (blockIdx.x * 256 + threadIdx.x) >> 6;  // node id, < 50000 exact
    int lane = threadIdx.x & 63;
    int g = lane >> 5;
    int c = lane & 31;
    int eb = c * V;

    float2v total[W2];
#pragma unroll
    for (int j = 0; j < W2; j++) total[j] = (float2v){0.f, 0.f};

#pragma unroll 1
    for (int r = 0; r < RR; r++) {
        const ushort* hsb = C + ((size_t)(2 * r) * NN) * NC;
        const ushort* hdb = C + ((size_t)(2 * r + 1) * NN) * NC;
        float2v hdv[W2], al[W2], acc[W2];
        ldrow<W2>(hdb + (size_t)wid * NC + eb, hdv);
#pragma unroll
        for (int j = 0; j < W2; j++) {
            al[j] = (float2v){a[r * NC + eb + 2 * j], a[r * NC + eb + 2 * j + 1]};
            acc[j] = (float2v){0.f, 0.f};
        }
        float den = 0.f;
        int e0 = offs[r * NN + wid];
        int dg = deg[r * NN + wid];
        int elast = e0 + dg - 1;
        int nit = (dg + 3) >> 2;
        for (int it = 0; it < nit; ++it) {
            int k0 = (it << 2) + g;
            int k1 = k0 + 2;
            int u0 = esrc[min(e0 + k0, elast)];
            int u1 = esrc[min(e0 + k1, elast)];
            float2v hv0[W2], hv1[W2];
            ldrow<W2>(hsb + (size_t)u0 * NC + eb, hv0);
            ldrow<W2>(hsb + (size_t)u1 * NC + eb, hv1);
            float s0 = hred8(edot<W2>(hv0, hdv, al));
            float s1 = hred8(edot<W2>(hv1, hdv, al));
            float p0 = (k0 < dg) ? __expf(s0) : 0.f;
            float p1 = (k1 < dg) ? __expf(s1) : 0.f;
            den += p0 + p1;
            float2v p0v = (float2v){p0, p0}, p1v = (float2v){p1, p1};
#pragma unroll
            for (int j = 0; j < W2; j++) acc[j] += p0v * hv0[j] + p1v * hv1[j];
        }
        // combine the 2 edge-groups
        den += __shfl_xor(den, 32);
        float inv = 1.f / (den + 1e-9f);
        float2v iv = (float2v){inv, inv};
#pragma unroll
        for (int j = 0; j < W2; j++) {
            float2v tt = acc[j];
            tt.x += __shfl_xor(tt.x, 32);
            tt.y += __shfl_xor(tt.y, 32);
            total[j] += tt * iv;
        }
    }

    if (g == 0) {
        if constexpr (L1) {
#pragma unroll
            for (int j = 0; j < W2; j++) {
                float v0 = total[j].x, v1 = total[j].y;
                outb[(size_t)wid * NC + eb + 2 * j]     = __float2bfloat16(v0 > 0.f ? v0 : 0.f);
                outb[(size_t)wid * NC + eb + 2 * j + 1] = __float2bfloat16(v1 > 0.f ? v1 : 0.f);
            }
        } else {
#pragma unroll
            for (int j = 0; j < W2; j++) {
                outf[(size_t)wid * NC + eb + 2 * j]     = total[j].x;
                outf[(size_t)wid * NC + eb + 2 * j + 1] = total[j].y;
            }
        }
    }
}

// ---------------- launch ----------------

extern "C" void kernel_launch(void* const* d_in, const int* in_sizes, int n_in,
                              void* d_out, int out_size, void* d_ws, size_t ws_size,
                              hipStream_t stream) {
    const float* x   = (const float*)d_in[0];
    const int*   src = (const int*)d_in[1];
    const int*   dst = (const int*)d_in[2];
    const float* W1s = (const float*)d_in[3];
    const float* W1d = (const float*)d_in[4];
    const float* a1  = (const float*)d_in[5];
    const float* W2s = (const float*)d_in[6];
    const float* W2d = (const float*)d_in[7];
    const float* a2  = (const float*)d_in[8];

    char* ws = (char*)d_ws;
    size_t off = 0;
    auto alloc = [&](size_t bytes) -> void* {
        void* p = ws + off;
        off += (bytes + 255) & ~(size_t)255;
        return p;
    };
    __hip_bfloat16* xb = (__hip_bfloat16*)alloc((size_t)NN * 128 * 2);
    __hip_bfloat16* hb = (__hip_bfloat16*)alloc((size_t)NN * 128 * 2);
    __hip_bfloat16* Cb = (__hip_bfloat16*)alloc((size_t)NN * 1536 * 2);  // 6 tables; L1 [N,128]x6, L2 [N,256]x6
    __hip_bfloat16* T1 = (__hip_bfloat16*)alloc((size_t)768 * 128 * 2);
    __hip_bfloat16* T2 = (__hip_bfloat16*)alloc((size_t)1536 * 128 * 2);
    int* deg  = (int*)alloc((size_t)TN * 4);
    int* offs = (int*)alloc((size_t)TN * 4);
    int* curs = (int*)alloc((size_t)TN * 4);
    int* esrc = (int*)alloc((size_t)RR * EE * 4);
    int* part = (int*)alloc(4096);

    float* outp = (float*)d_out;

    // conversions / weight packing
    conv_bf16_kernel<<<25000, 256, 0, stream>>>(x, xb, NN * 128);
    transpose_w_kernel<<<192, 256, 0, stream>>>(W1s, T1, 128, 0);
    transpose_w_kernel<<<192, 256, 0, stream>>>(W1d, T1, 128, 128);
    transpose_w_kernel<<<384, 256, 0, stream>>>(W2s, T2, 256, 0);
    transpose_w_kernel<<<384, 256, 0, stream>>>(W2d, T2, 256, 256);

    // CSR build (shared by both layers)
    hipMemsetAsync(deg, 0, (size_t)TN * 4, stream);
    hist_kernel<<<(RR * EE) / 256, 256, 0, stream>>>(dst, deg);
    scan1_kernel<<<NCHUNK, 256, 0, stream>>>(deg, part);
    scan2_kernel<<<1, 1, 0, stream>>>(part);
    scan3_kernel<<<NCHUNK, 256, 0, stream>>>(deg, part, offs, curs);
    scatter_kernel<<<dim3((RR * EE) / 256, 4), 256, 0, stream>>>(src, dst, curs, esrc);

    // Layer 1: GEMM [N,128]x[128,768] -> 6 compact [N,128] tables; agg fuses relu+bf16 -> hb
    gemm_kernel<<<dim3(782, 12), 256, 0, stream>>>(xb, T1, Cb, NN, 7);
    agg_kernel<2, true><<<12500, 256, 0, stream>>>((const ushort*)Cb, a1, offs, deg, esrc,
                                                   nullptr, hb);

    // Layer 2: GEMM [N,128]x[128,1536] -> 6 compact [N,256] tables; agg -> f32 d_out
    gemm_kernel<<<dim3(782, 24), 256, 0, stream>>>(hb, T2, Cb, NN, 8);
    agg_kernel<4, false><<<12500, 256, 0, stream>>>((const ushort*)Cb, a2, offs, deg, esrc,
                                                    outp, nullptr);
}

// Round 6
// 635.334 us; speedup vs baseline: 1.0363x; 1.0058x over previous
//
#include <hip/hip_runtime.h>
#include <hip/hip_bf16.h>

#define NN 50000
#define HH 4
#define RR 3
#define EE 524288      // 2^19
#define ESHIFT 19
#define TN (RR*NN)     // 150000
#define NCHUNK ((TN + 1023)/1024)  // 147

typedef __attribute__((ext_vector_type(8))) short short8;
typedef __attribute__((ext_vector_type(4))) float float4v;
typedef __attribute__((ext_vector_type(2))) float float2v;

// ---------------- conversion kernels ----------------

__global__ void conv_bf16_kernel(const float* __restrict__ in, __hip_bfloat16* __restrict__ out, int n) {
    int i = blockIdx.x * 256 + threadIdx.x;
    if (i < n) out[i] = __float2bfloat16(in[i]);
}

// W: [3][128][NC] f32 -> T: [3*2*NC rows][128] bf16; row (r*2*NC + colOff + n), col k.
__global__ void transpose_w_kernel(const float* __restrict__ W, __hip_bfloat16* __restrict__ T,
                                   int NC, int colOff) {
    int i = blockIdx.x * 256 + threadIdx.x;   // exact: 3*128*NC
    int per = 128 * NC;
    int r = i / per;
    int rem = i - r * per;
    int k = rem / NC;
    int n = rem - k * NC;
    T[(size_t)(r * 2 * NC + colOff + n) * 128 + k] = __float2bfloat16(W[i]);
}

// ---------------- CSR build ----------------

__global__ void hist_kernel(const int* __restrict__ dst, int* __restrict__ deg) {
    int i = blockIdx.x * 256 + threadIdx.x;   // < 3E exact
    int r = i >> ESHIFT;
    atomicAdd(&deg[r * NN + dst[i]], 1);
}

__global__ void scan1_kernel(const int* __restrict__ deg, int* __restrict__ part) {
    __shared__ int s[256];
    int t = threadIdx.x;
    int base = blockIdx.x * 1024 + t * 4;
    int sum = 0;
#pragma unroll
    for (int j = 0; j < 4; j++) {
        int idx = base + j;
        sum += (idx < TN) ? deg[idx] : 0;
    }
    s[t] = sum;
    __syncthreads();
    for (int off = 128; off > 0; off >>= 1) {
        if (t < off) s[t] += s[t + off];
        __syncthreads();
    }
    if (t == 0) part[blockIdx.x] = s[0];
}

__global__ void scan2_kernel(int* part) {
    int run = 0;
    for (int i = 0; i < NCHUNK; i++) {
        int v = part[i];
        part[i] = run;
        run += v;
    }
}

__global__ void scan3_kernel(const int* __restrict__ deg, const int* __restrict__ part,
                             int* __restrict__ offs, int* __restrict__ curs) {
    __shared__ int s[256];
    int t = threadIdx.x;
    int base = blockIdx.x * 1024 + t * 4;
    int v[4];
    int tsum = 0;
#pragma unroll
    for (int j = 0; j < 4; j++) {
        int idx = base + j;
        v[j] = (idx < TN) ? deg[idx] : 0;
        tsum += v[j];
    }
    s[t] = tsum;
    __syncthreads();
    for (int off = 1; off < 256; off <<= 1) {
        int x = (t >= off) ? s[t - off] : 0;
        __syncthreads();
        s[t] += x;
        __syncthreads();
    }
    int excl = s[t] - tsum + part[blockIdx.x];
    int run = excl;
#pragma unroll
    for (int j = 0; j < 4; j++) {
        int idx = base + j;
        if (idx < TN) {
            offs[idx] = run;
            curs[idx] = run;
            run += v[j];
        }
    }
}

// Pass-split scatter: blockIdx.y = dst-range pass (4 x 12500 nodes) -> L2-resident write window.
__global__ void scatter_kernel(const int* __restrict__ src, const int* __restrict__ dst,
                               int* __restrict__ curs, int* __restrict__ esrc) {
    int i = blockIdx.x * 256 + threadIdx.x;   // < 3E exact
    int p = blockIdx.y;
    int d = dst[i];
    if ((unsigned)(d - p * 12500) < 12500u) {
        int r = i >> ESHIFT;
        int pos = atomicAdd(&curs[r * NN + d], 1);
        esrc[pos] = src[i];
    }
}

// ---------------- GEMM ----------------
// C tables layout: 6 tables [M, NCsub] bf16, table id = global_col >> nshift
// (order: r0_src, r0_dst, r1_src, r1_dst, r2_src, r2_dst).

__launch_bounds__(256)
__global__ void gemm_kernel(const __hip_bfloat16* __restrict__ A,
                            const __hip_bfloat16* __restrict__ Bt,   // [NCtot,128]
                            __hip_bfloat16* __restrict__ C,
                            int M, int nshift) {
    __shared__ __hip_bfloat16 Bs[64 * 136];
    int tile_m = blockIdx.x * 64;
    int tile_n = blockIdx.y * 64;
    int t = threadIdx.x;

    {
        const uint4* gsrc = (const uint4*)(Bt + (size_t)tile_n * 128);
        for (int e = t; e < 64 * 16; e += 256) {
            int n = e >> 4, c = e & 15;
            uint4 val = gsrc[n * 16 + c];
            *(uint4*)(&Bs[n * 136 + c * 8]) = val;
        }
    }
    __syncthreads();

    int w = t >> 6, lane = t & 63;
    int m16 = lane & 15, quad = lane >> 4;
    int row = tile_m + w * 16 + m16;
    int rowc = row < M ? row : M - 1;

    short8 a[4];
    const short8* ap = (const short8*)(A + (size_t)rowc * 128);
#pragma unroll
    for (int kf = 0; kf < 4; kf++) a[kf] = ap[quad + kf * 4];

    float4v acc[4];
#pragma unroll
    for (int ct = 0; ct < 4; ct++) {
        acc[ct] = (float4v){0.f, 0.f, 0.f, 0.f};
        const short8* bp = (const short8*)(Bs + (ct * 16 + m16) * 136);
#pragma unroll
        for (int kf = 0; kf < 4; kf++) {
            short8 b = bp[quad + kf * 4];
            acc[ct] = __builtin_amdgcn_mfma_f32_16x16x32_bf16(a[kf], b, acc[ct], 0, 0, 0);
        }
    }

    int cmask = (1 << nshift) - 1;
#pragma unroll
    for (int ct = 0; ct < 4; ct++) {
        int col = tile_n + ct * 16 + m16;
        int tbl = col >> nshift;
        int cc = col & cmask;
        size_t base = ((size_t)tbl * M) << nshift;
#pragma unroll
        for (int rg = 0; rg < 4; rg++) {
            int rr = tile_m + w * 16 + quad * 4 + rg;
            if (rr < M) C[base + (((size_t)rr) << nshift) + cc] = __float2bfloat16(acc[ct][rg]);
        }
    }
}

// ---------------- fused per-node softmax + aggregation ----------------
// One wave per node, 64 lanes per edge (round-3 layout): lane holds V = NC/64
// channels (L1: V=2/W2=1, L2: V=4/W2=2). Head = 16-lane group -> score reduce
// shfl_xor 1,2,4,8. Edge loop unrolled x4 -> 4 independent gather chains
// (round-3 MLP) with packed-f32 math (round-5 cost). No cross-group epilogue.

template <int W2>
__device__ inline void ldrow(const ushort* __restrict__ p, float2v* hv) {
    if constexpr (W2 == 1) {   // V=2: 4 bytes
        uint pk = *(const uint*)p;
        hv[0] = (float2v){__uint_as_float(pk << 16), __uint_as_float(pk & 0xffff0000u)};
    } else {                   // V=4: 8 bytes
        uint2 pk = *(const uint2*)p;
        hv[0] = (float2v){__uint_as_float(pk.x << 16), __uint_as_float(pk.x & 0xffff0000u)};
        hv[1] = (float2v){__uint_as_float(pk.y << 16), __uint_as_float(pk.y & 0xffff0000u)};
    }
}

template <int W2>
__device__ inline float edot(const float2v* hv, const float2v* hdv, const float2v* al) {
    float2v s = (float2v){0.f, 0.f};
#pragma unroll
    for (int j = 0; j < W2; j++) {
        float2v m = hv[j] + hdv[j];
        float2v lr = __builtin_elementwise_max(m, 0.2f * m);
        s += lr * al[j];
    }
    return s.x + s.y;
}

__device__ inline float hred16(float s) {
    s += __shfl_xor(s, 1);
    s += __shfl_xor(s, 2);
    s += __shfl_xor(s, 4);
    s += __shfl_xor(s, 8);
    return s;
}

template <int W2, bool L1>
__launch_bounds__(256)
__global__ void agg_kernel(const ushort* __restrict__ C,
                           const float* __restrict__ a,            // [R][NC]
                           const int* __restrict__ offs, const int* __restrict__ deg,
                           const int* __restrict__ esrc,
                           float* __restrict__ outf, __hip_bfloat16* __restrict__ outb) {
    const int V = 2 * W2;
    const int NC = 64 * V;
    int wid = (blockIdx.x * 256 + threadIdx.x) >> 6;  // node id, < 50000 exact
    int lane = threadIdx.x & 63;
    int eb = lane * V;

    float2v total[W2];
#pragma unroll
    for (int j = 0; j < W2; j++) total[j] = (float2v){0.f, 0.f};

#pragma unroll 1
    for (int r = 0; r < RR; r++) {
        const ushort* hsb = C + ((size_t)(2 * r) * NN) * NC + eb;
        const ushort* hdb = C + ((size_t)(2 * r + 1) * NN) * NC + eb;
        float2v hdv[W2], al[W2], acc[W2];
        ldrow<W2>(hdb + (size_t)wid * NC, hdv);
#pragma unroll
        for (int j = 0; j < W2; j++) {
            al[j] = (float2v){a[r * NC + eb + 2 * j], a[r * NC + eb + 2 * j + 1]};
            acc[j] = (float2v){0.f, 0.f};
        }
        float den = 0.f;
        int e0 = offs[r * NN + wid];
        int dg = deg[r * NN + wid];
        int elast = e0 + dg - 1;
        int nit = (dg + 3) >> 2;
        for (int it = 0; it < nit; ++it) {
            int k = it << 2;
            int u0 = esrc[e0 + k];
            int u1 = esrc[min(e0 + k + 1, elast)];
            int u2 = esrc[min(e0 + k + 2, elast)];
            int u3 = esrc[min(e0 + k + 3, elast)];
            float2v hv0[W2], hv1[W2], hv2[W2], hv3[W2];
            ldrow<W2>(hsb + (size_t)u0 * NC, hv0);
            ldrow<W2>(hsb + (size_t)u1 * NC, hv1);
            ldrow<W2>(hsb + (size_t)u2 * NC, hv2);
            ldrow<W2>(hsb + (size_t)u3 * NC, hv3);
            float s0 = hred16(edot<W2>(hv0, hdv, al));
            float s1 = hred16(edot<W2>(hv1, hdv, al));
            float s2 = hred16(edot<W2>(hv2, hdv, al));
            float s3 = hred16(edot<W2>(hv3, hdv, al));
            float p0 = __expf(s0);
            float p1 = (k + 1 < dg) ? __expf(s1) : 0.f;
            float p2 = (k + 2 < dg) ? __expf(s2) : 0.f;
            float p3 = (k + 3 < dg) ? __expf(s3) : 0.f;
            den += (p0 + p1) + (p2 + p3);
            float2v p0v = (float2v){p0, p0}, p1v = (float2v){p1, p1};
            float2v p2v = (float2v){p2, p2}, p3v = (float2v){p3, p3};
#pragma unroll
            for (int j = 0; j < W2; j++)
                acc[j] += (p0v * hv0[j] + p1v * hv1[j]) + (p2v * hv2[j] + p3v * hv3[j]);
        }
        float inv = 1.f / (den + 1e-9f);
        float2v iv = (float2v){inv, inv};
#pragma unroll
        for (int j = 0; j < W2; j++) total[j] += acc[j] * iv;
    }

    if constexpr (L1) {
#pragma unroll
        for (int j = 0; j < W2; j++) {
            float v0 = total[j].x, v1 = total[j].y;
            outb[(size_t)wid * NC + eb + 2 * j]     = __float2bfloat16(v0 > 0.f ? v0 : 0.f);
            outb[(size_t)wid * NC + eb + 2 * j + 1] = __float2bfloat16(v1 > 0.f ? v1 : 0.f);
        }
    } else {
#pragma unroll
        for (int j = 0; j < W2; j++) {
            outf[(size_t)wid * NC + eb + 2 * j]     = total[j].x;
            outf[(size_t)wid * NC + eb + 2 * j + 1] = total[j].y;
        }
    }
}

// ---------------- launch ----------------

extern "C" void kernel_launch(void* const* d_in, const int* in_sizes, int n_in,
                              void* d_out, int out_size, void* d_ws, size_t ws_size,
                              hipStream_t stream) {
    const float* x   = (const float*)d_in[0];
    const int*   src = (const int*)d_in[1];
    const int*   dst = (const int*)d_in[2];
    const float* W1s = (const float*)d_in[3];
    const float* W1d = (const float*)d_in[4];
    const float* a1  = (const float*)d_in[5];
    const float* W2s = (const float*)d_in[6];
    const float* W2d = (const float*)d_in[7];
    const float* a2  = (const float*)d_in[8];

    char* ws = (char*)d_ws;
    size_t off = 0;
    auto alloc = [&](size_t bytes) -> void* {
        void* p = ws + off;
        off += (bytes + 255) & ~(size_t)255;
        return p;
    };
    __hip_bfloat16* xb = (__hip_bfloat16*)alloc((size_t)NN * 128 * 2);
    __hip_bfloat16* hb = (__hip_bfloat16*)alloc((size_t)NN * 128 * 2);
    __hip_bfloat16* Cb = (__hip_bfloat16*)alloc((size_t)NN * 1536 * 2);  // 6 tables; L1 [N,128]x6, L2 [N,256]x6
    __hip_bfloat16* T1 = (__hip_bfloat16*)alloc((size_t)768 * 128 * 2);
    __hip_bfloat16* T2 = (__hip_bfloat16*)alloc((size_t)1536 * 128 * 2);
    int* deg  = (int*)alloc((size_t)TN * 4);
    int* offs = (int*)alloc((size_t)TN * 4);
    int* curs = (int*)alloc((size_t)TN * 4);
    int* esrc = (int*)alloc((size_t)RR * EE * 4);
    int* part = (int*)alloc(4096);

    float* outp = (float*)d_out;

    // conversions / weight packing
    conv_bf16_kernel<<<25000, 256, 0, stream>>>(x, xb, NN * 128);
    transpose_w_kernel<<<192, 256, 0, stream>>>(W1s, T1, 128, 0);
    transpose_w_kernel<<<192, 256, 0, stream>>>(W1d, T1, 128, 128);
    transpose_w_kernel<<<384, 256, 0, stream>>>(W2s, T2, 256, 0);
    transpose_w_kernel<<<384, 256, 0, stream>>>(W2d, T2, 256, 256);

    // CSR build (shared by both layers)
    hipMemsetAsync(deg, 0, (size_t)TN * 4, stream);
    hist_kernel<<<(RR * EE) / 256, 256, 0, stream>>>(dst, deg);
    scan1_kernel<<<NCHUNK, 256, 0, stream>>>(deg, part);
    scan2_kernel<<<1, 1, 0, stream>>>(part);
    scan3_kernel<<<NCHUNK, 256, 0, stream>>>(deg, part, offs, curs);
    scatter_kernel<<<dim3((RR * EE) / 256, 4), 256, 0, stream>>>(src, dst, curs, esrc);

    // Layer 1: GEMM [N,128]x[128,768] -> 6 compact [N,128] tables; agg fuses relu+bf16 -> hb
    gemm_kernel<<<dim3(782, 12), 256, 0, stream>>>(xb, T1, Cb, NN, 7);
    agg_kernel<1, true><<<12500, 256, 0, stream>>>((const ushort*)Cb, a1, offs, deg, esrc,
                                                   nullptr, hb);

    // Layer 2: GEMM [N,128]x[128,1536] -> 6 compact [N,256] tables; agg -> f32 d_out
    gemm_kernel<<<dim3(782, 24), 256, 0, stream>>>(hb, T2, Cb, NN, 8);
    agg_kernel<2, false><<<12500, 256, 0, stream>>>((const ushort*)Cb, a2, offs, deg, esrc,
                                                    outp, nullptr);
}

// Round 7
// 629.254 us; speedup vs baseline: 1.0463x; 1.0097x over previous
//
#include <hip/hip_runtime.h>
#include <hip/hip_bf16.h>

#define NN 50000
#define HH 4
#define RR 3
#define EE 524288      // 2^19
#define ESHIFT 19
#define TN (RR*NN)     // 150000
#define NCHUNK ((TN + 1023)/1024)  // 147
#define LOG2E 1.4426950408889634f

typedef __attribute__((ext_vector_type(8))) short short8;
typedef __attribute__((ext_vector_type(4))) float float4v;
typedef __attribute__((ext_vector_type(2))) float float2v;

// ---------------- conversion kernels ----------------

__global__ void conv_bf16_kernel(const float* __restrict__ in, __hip_bfloat16* __restrict__ out, int n) {
    int i = blockIdx.x * 256 + threadIdx.x;
    if (i < n) out[i] = __float2bfloat16(in[i]);
}

// W: [3][128][NC] f32 -> T: [3*2*NC rows][128] bf16; row (r*2*NC + colOff + n), col k.
__global__ void transpose_w_kernel(const float* __restrict__ W, __hip_bfloat16* __restrict__ T,
                                   int NC, int colOff) {
    int i = blockIdx.x * 256 + threadIdx.x;   // exact: 3*128*NC
    int per = 128 * NC;
    int r = i / per;
    int rem = i - r * per;
    int k = rem / NC;
    int n = rem - k * NC;
    T[(size_t)(r * 2 * NC + colOff + n) * 128 + k] = __float2bfloat16(W[i]);
}

// ---------------- CSR build ----------------

__global__ void hist_kernel(const int* __restrict__ dst, int* __restrict__ deg) {
    int i = blockIdx.x * 256 + threadIdx.x;   // < 3E exact
    int r = i >> ESHIFT;
    atomicAdd(&deg[r * NN + dst[i]], 1);
}

__global__ void scan1_kernel(const int* __restrict__ deg, int* __restrict__ part) {
    __shared__ int s[256];
    int t = threadIdx.x;
    int base = blockIdx.x * 1024 + t * 4;
    int sum = 0;
#pragma unroll
    for (int j = 0; j < 4; j++) {
        int idx = base + j;
        sum += (idx < TN) ? deg[idx] : 0;
    }
    s[t] = sum;
    __syncthreads();
    for (int off = 128; off > 0; off >>= 1) {
        if (t < off) s[t] += s[t + off];
        __syncthreads();
    }
    if (t == 0) part[blockIdx.x] = s[0];
}

__global__ void scan2_kernel(int* part) {
    int run = 0;
    for (int i = 0; i < NCHUNK; i++) {
        int v = part[i];
        part[i] = run;
        run += v;
    }
}

__global__ void scan3_kernel(const int* __restrict__ deg, const int* __restrict__ part,
                             int* __restrict__ offs, int* __restrict__ curs) {
    __shared__ int s[256];
    int t = threadIdx.x;
    int base = blockIdx.x * 1024 + t * 4;
    int v[4];
    int tsum = 0;
#pragma unroll
    for (int j = 0; j < 4; j++) {
        int idx = base + j;
        v[j] = (idx < TN) ? deg[idx] : 0;
        tsum += v[j];
    }
    s[t] = tsum;
    __syncthreads();
    for (int off = 1; off < 256; off <<= 1) {
        int x = (t >= off) ? s[t - off] : 0;
        __syncthreads();
        s[t] += x;
        __syncthreads();
    }
    int excl = s[t] - tsum + part[blockIdx.x];
    int run = excl;
#pragma unroll
    for (int j = 0; j < 4; j++) {
        int idx = base + j;
        if (idx < TN) {
            offs[idx] = run;
            curs[idx] = run;
            run += v[j];
        }
    }
}

// Pass-split scatter: blockIdx.y = dst-range pass (4 x 12500 nodes) -> L2-resident write window.
// Stores src<<8 = row byte offset at layer-1 scale (256 B rows); layer-2 shifts <<1.
__global__ void scatter_kernel(const int* __restrict__ src, const int* __restrict__ dst,
                               int* __restrict__ curs, int* __restrict__ esrc) {
    int i = blockIdx.x * 256 + threadIdx.x;   // < 3E exact
    int p = blockIdx.y;
    int d = dst[i];
    if ((unsigned)(d - p * 12500) < 12500u) {
        int r = i >> ESHIFT;
        int pos = atomicAdd(&curs[r * NN + d], 1);
        esrc[pos] = src[i] << 8;
    }
}

// ---------------- GEMM ----------------
// C tables layout: 6 tables [M, NCsub] bf16, table id = global_col >> nshift
// (order: r0_src, r0_dst, r1_src, r1_dst, r2_src, r2_dst).

__launch_bounds__(256)
__global__ void gemm_kernel(const __hip_bfloat16* __restrict__ A,
                            const __hip_bfloat16* __restrict__ Bt,   // [NCtot,128]
                            __hip_bfloat16* __restrict__ C,
                            int M, int nshift) {
    __shared__ __hip_bfloat16 Bs[64 * 136];
    int tile_m = blockIdx.x * 64;
    int tile_n = blockIdx.y * 64;
    int t = threadIdx.x;

    {
        const uint4* gsrc = (const uint4*)(Bt + (size_t)tile_n * 128);
        for (int e = t; e < 64 * 16; e += 256) {
            int n = e >> 4, c = e & 15;
            uint4 val = gsrc[n * 16 + c];
            *(uint4*)(&Bs[n * 136 + c * 8]) = val;
        }
    }
    __syncthreads();

    int w = t >> 6, lane = t & 63;
    int m16 = lane & 15, quad = lane >> 4;
    int row = tile_m + w * 16 + m16;
    int rowc = row < M ? row : M - 1;

    short8 a[4];
    const short8* ap = (const short8*)(A + (size_t)rowc * 128);
#pragma unroll
    for (int kf = 0; kf < 4; kf++) a[kf] = ap[quad + kf * 4];

    float4v acc[4];
#pragma unroll
    for (int ct = 0; ct < 4; ct++) {
        acc[ct] = (float4v){0.f, 0.f, 0.f, 0.f};
        const short8* bp = (const short8*)(Bs + (ct * 16 + m16) * 136);
#pragma unroll
        for (int kf = 0; kf < 4; kf++) {
            short8 b = bp[quad + kf * 4];
            acc[ct] = __builtin_amdgcn_mfma_f32_16x16x32_bf16(a[kf], b, acc[ct], 0, 0, 0);
        }
    }

    int cmask = (1 << nshift) - 1;
#pragma unroll
    for (int ct = 0; ct < 4; ct++) {
        int col = tile_n + ct * 16 + m16;
        int tbl = col >> nshift;
        int cc = col & cmask;
        size_t base = ((size_t)tbl * M) << nshift;
#pragma unroll
        for (int rg = 0; rg < 4; rg++) {
            int rr = tile_m + w * 16 + quad * 4 + rg;
            if (rr < M) C[base + (((size_t)rr) << nshift) + cc] = __float2bfloat16(acc[ct][rg]);
        }
    }
}

// ---------------- fused per-node softmax + aggregation ----------------
// One wave per node; 2 edge-halves (g = lane>>5) x 32 channel-slices (c = lane&31).
// V = 2*W2 channels/lane; NC = 64*W2 (L1: W2=2, L2: W2=4).
// Head = 8 lanes (NC/4 ch) -> score reduce shfl_xor 1,2,4 (1.5 shuffles/edge).
// Unroll x4 per half -> 8 edges in flight (4 independent chains per lane).
// esrc holds byte offsets (src<<8); SH adjusts for row size. a prescaled by
// log2e -> raw v_exp_f32 (2^(s*log2e) = e^s, softmax exact).

template <int W2>
__device__ inline void ldrow(const char* __restrict__ p, float2v* hv) {
    if constexpr (W2 == 2) {   // 4 ch: 8 bytes
        uint2 pk = *(const uint2*)p;
        hv[0] = (float2v){__uint_as_float(pk.x << 16), __uint_as_float(pk.x & 0xffff0000u)};
        hv[1] = (float2v){__uint_as_float(pk.y << 16), __uint_as_float(pk.y & 0xffff0000u)};
    } else {                   // 8 ch: 16 bytes
        uint4 pk = *(const uint4*)p;
        hv[0] = (float2v){__uint_as_float(pk.x << 16), __uint_as_float(pk.x & 0xffff0000u)};
        hv[1] = (float2v){__uint_as_float(pk.y << 16), __uint_as_float(pk.y & 0xffff0000u)};
        hv[2] = (float2v){__uint_as_float(pk.z << 16), __uint_as_float(pk.z & 0xffff0000u)};
        hv[3] = (float2v){__uint_as_float(pk.w << 16), __uint_as_float(pk.w & 0xffff0000u)};
    }
}

template <int W2>
__device__ inline float edot(const float2v* hv, const float2v* hdv, const float2v* al) {
    float2v s = (float2v){0.f, 0.f};
#pragma unroll
    for (int j = 0; j < W2; j++) {
        float2v m = hv[j] + hdv[j];
        float2v lr = __builtin_elementwise_max(m, 0.2f * m);
        s += lr * al[j];
    }
    return s.x + s.y;
}

__device__ inline float hred8(float s) {
    s += __shfl_xor(s, 1);
    s += __shfl_xor(s, 2);
    s += __shfl_xor(s, 4);
    return s;
}

template <int W2, bool L1, int SH>
__launch_bounds__(256)
__global__ void agg_kernel(const char* __restrict__ C,               // bf16 tables, byte-addressed
                           const float* __restrict__ a,              // [R][NC]
                           const int* __restrict__ offs, const int* __restrict__ deg,
                           const int* __restrict__ esrc,             // byte offsets (src<<8)
                           float* __restrict__ outf, __hip_bfloat16* __restrict__ outb) {
    const int V = 2 * W2;
    const int NC = 32 * V;
    const int ROWB = NC * 2;                          // row bytes
    int wid = (blockIdx.x * 256 + threadIdx.x) >> 6;  // node id, < 50000 exact
    int lane = threadIdx.x & 63;
    int g = lane >> 5;
    int c = lane & 31;
    int eb = c * V;            // channel offset
    int ebb = eb * 2;          // byte offset within row

    float2v total[W2];
#pragma unroll
    for (int j = 0; j < W2; j++) total[j] = (float2v){0.f, 0.f};

#pragma unroll 1
    for (int r = 0; r < RR; r++) {
        const char* hsb = C + (size_t)(2 * r) * NN * ROWB + ebb;
        const char* hdb = C + (size_t)(2 * r + 1) * NN * ROWB + ebb;
        float2v hdv[W2], al[W2], acc[W2];
        ldrow<W2>(hdb + (size_t)wid * ROWB, hdv);
#pragma unroll
        for (int j = 0; j < W2; j++) {
            al[j] = (float2v){a[r * NC + eb + 2 * j] * LOG2E, a[r * NC + eb + 2 * j + 1] * LOG2E};
            acc[j] = (float2v){0.f, 0.f};
        }
        float den = 0.f;
        int e0 = offs[r * NN + wid];
        int dg = deg[r * NN + wid];
        int elast = e0 + dg - 1;
        int nit = (dg + 7) >> 3;
        for (int it = 0; it < nit; ++it) {
            int k = (it << 3) + (g << 2);   // this half's first edge slot
            int u0 = esrc[min(e0 + k, elast)];
            int u1 = esrc[min(e0 + k + 1, elast)];
            int u2 = esrc[min(e0 + k + 2, elast)];
            int u3 = esrc[min(e0 + k + 3, elast)];
            float2v hv0[W2], hv1[W2], hv2[W2], hv3[W2];
            ldrow<W2>(hsb + ((size_t)(unsigned)u0 << SH), hv0);
            ldrow<W2>(hsb + ((size_t)(unsigned)u1 << SH), hv1);
            ldrow<W2>(hsb + ((size_t)(unsigned)u2 << SH), hv2);
            ldrow<W2>(hsb + ((size_t)(unsigned)u3 << SH), hv3);
            float s0 = hred8(edot<W2>(hv0, hdv, al));
            float s1 = hred8(edot<W2>(hv1, hdv, al));
            float s2 = hred8(edot<W2>(hv2, hdv, al));
            float s3 = hred8(edot<W2>(hv3, hdv, al));
            float p0 = (k     < dg) ? __builtin_amdgcn_exp2f(s0) : 0.f;
            float p1 = (k + 1 < dg) ? __builtin_amdgcn_exp2f(s1) : 0.f;
            float p2 = (k + 2 < dg) ? __builtin_amdgcn_exp2f(s2) : 0.f;
            float p3 = (k + 3 < dg) ? __builtin_amdgcn_exp2f(s3) : 0.f;
            den += (p0 + p1) + (p2 + p3);
            float2v p0v = (float2v){p0, p0}, p1v = (float2v){p1, p1};
            float2v p2v = (float2v){p2, p2}, p3v = (float2v){p3, p3};
#pragma unroll
            for (int j = 0; j < W2; j++)
                acc[j] += (p0v * hv0[j] + p1v * hv1[j]) + (p2v * hv2[j] + p3v * hv3[j]);
        }
        // combine the two halves
        den += __shfl_xor(den, 32);
        float inv = 1.f / (den + 1e-9f);
        float2v iv = (float2v){inv, inv};
#pragma unroll
        for (int j = 0; j < W2; j++) {
            float2v tt = acc[j];
            tt.x += __shfl_xor(tt.x, 32);
            tt.y += __shfl_xor(tt.y, 32);
            total[j] += tt * iv;
        }
    }

    if (g == 0) {
        if constexpr (L1) {
#pragma unroll
            for (int j = 0; j < W2; j++) {
                float v0 = total[j].x, v1 = total[j].y;
                outb[(size_t)wid * NC + eb + 2 * j]     = __float2bfloat16(v0 > 0.f ? v0 : 0.f);
                outb[(size_t)wid * NC + eb + 2 * j + 1] = __float2bfloat16(v1 > 0.f ? v1 : 0.f);
            }
        } else {
#pragma unroll
            for (int j = 0; j < W2; j++) {
                outf[(size_t)wid * NC + eb + 2 * j]     = total[j].x;
                outf[(size_t)wid * NC + eb + 2 * j + 1] = total[j].y;
            }
        }
    }
}

// ---------------- launch ----------------

extern "C" void kernel_launch(void* const* d_in, const int* in_sizes, int n_in,
                              void* d_out, int out_size, void* d_ws, size_t ws_size,
                              hipStream_t stream) {
    const float* x   = (const float*)d_in[0];
    const int*   src = (const int*)d_in[1];
    const int*   dst = (const int*)d_in[2];
    const float* W1s = (const float*)d_in[3];
    const float* W1d = (const float*)d_in[4];
    const float* a1  = (const float*)d_in[5];
    const float* W2s = (const float*)d_in[6];
    const float* W2d = (const float*)d_in[7];
    const float* a2  = (const float*)d_in[8];

    char* ws = (char*)d_ws;
    size_t off = 0;
    auto alloc = [&](size_t bytes) -> void* {
        void* p = ws + off;
        off += (bytes + 255) & ~(size_t)255;
        return p;
    };
    __hip_bfloat16* xb = (__hip_bfloat16*)alloc((size_t)NN * 128 * 2);
    __hip_bfloat16* hb = (__hip_bfloat16*)alloc((size_t)NN * 128 * 2);
    __hip_bfloat16* Cb = (__hip_bfloat16*)alloc((size_t)NN * 1536 * 2);  // 6 tables; L1 [N,128]x6, L2 [N,256]x6
    __hip_bfloat16* T1 = (__hip_bfloat16*)alloc((size_t)768 * 128 * 2);
    __hip_bfloat16* T2 = (__hip_bfloat16*)alloc((size_t)1536 * 128 * 2);
    int* deg  = (int*)alloc((size_t)TN * 4);
    int* offs = (int*)alloc((size_t)TN * 4);
    int* curs = (int*)alloc((size_t)TN * 4);
    int* esrc = (int*)alloc((size_t)RR * EE * 4);
    int* part = (int*)alloc(4096);

    float* outp = (float*)d_out;

    // conversions / weight packing
    conv_bf16_kernel<<<25000, 256, 0, stream>>>(x, xb, NN * 128);
    transpose_w_kernel<<<192, 256, 0, stream>>>(W1s, T1, 128, 0);
    transpose_w_kernel<<<192, 256, 0, stream>>>(W1d, T1, 128, 128);
    transpose_w_kernel<<<384, 256, 0, stream>>>(W2s, T2, 256, 0);
    transpose_w_kernel<<<384, 256, 0, stream>>>(W2d, T2, 256, 256);

    // CSR build (shared by both layers)
    hipMemsetAsync(deg, 0, (size_t)TN * 4, stream);
    hist_kernel<<<(RR * EE) / 256, 256, 0, stream>>>(dst, deg);
    scan1_kernel<<<NCHUNK, 256, 0, stream>>>(deg, part);
    scan2_kernel<<<1, 1, 0, stream>>>(part);
    scan3_kernel<<<NCHUNK, 256, 0, stream>>>(deg, part, offs, curs);
    scatter_kernel<<<dim3((RR * EE) / 256, 4), 256, 0, stream>>>(src, dst, curs, esrc);

    // Layer 1: GEMM [N,128]x[128,768] -> 6 compact [N,128] tables; agg fuses relu+bf16 -> hb
    gemm_kernel<<<dim3(782, 12), 256, 0, stream>>>(xb, T1, Cb, NN, 7);
    agg_kernel<2, true, 0><<<12500, 256, 0, stream>>>((const char*)Cb, a1, offs, deg, esrc,
                                                      nullptr, hb);

    // Layer 2: GEMM [N,128]x[128,1536] -> 6 compact [N,256] tables; agg -> f32 d_out
    gemm_kernel<<<dim3(782, 24), 256, 0, stream>>>(hb, T2, Cb, NN, 8);
    agg_kernel<4, false, 1><<<12500, 256, 0, stream>>>((const char*)Cb, a2, offs, deg, esrc,
                                                       outp, nullptr);
}